// Round 1
// baseline (9123.632 us; speedup 1.0000x reference)
//
#include <hip/hip_runtime.h>
#include <stdint.h>
#include <stddef.h>

// LSTM: B=64, T=512, I=H=1024. fp32 in/out, bf16 MFMA compute internally.
//
// Pipeline (all on `stream`):
//   k_init    : zero h double-buffer + barrier counters (ws is poisoned 0xAA)
//   k_cvt_x   : x fp32 -> bf16 (same [B][T][I] layout)
//   k_cvt_w   : W*/U* fp32 -> bf16, rows reordered to (wg, gate, local-col)
//   k_gemm    : xg[t][wg][b][c] = x @ Wcat^T   (m97-style 128x128 bf16 GEMM)
//   k_lstm    : persistent 128-WG recurrence; U in VGPRs, c in VGPRs,
//               flag-barrier per step (128 WGs <= 256 CUs => co-resident).

typedef unsigned short u16;
typedef unsigned int u32;
typedef short bf16x8 __attribute__((ext_vector_type(8)));
typedef float f32x4 __attribute__((ext_vector_type(4)));

#define B_ 64
#define T_ 512
#define I_ 1024
#define H_ 1024
#define NWG 128
#define BTH (B_ * T_ * H_)

// ws layout (bytes)
#define OFF_XB 0UL                 // 64 MB  : x bf16 [64][512][1024]
#define OFF_WT 67108864UL          // 8 MB   : Wcat bf16, reordered rows [4096][1024]
#define OFF_UT 75497472UL          // 8 MB   : Ucat bf16, reordered rows [4096][1024]
#define OFF_XG 83886080UL          // 256 MB : xg bf16 [512][128][64][32]
#define OFF_HB 352321536UL         // 256 KB : h double buffer bf16 2x[64][1024]
#define OFF_CNT 352583680UL        // 2 KB   : barrier counters int[512]

__device__ __forceinline__ u16 f2bf(float f) {
  u32 u = __builtin_bit_cast(u32, f);
  return (u16)((u + 0x7FFFu + ((u >> 16) & 1u)) >> 16);
}
__device__ __forceinline__ float bf2f(u16 h) {
  u32 u = ((u32)h) << 16;
  return __builtin_bit_cast(float, u);
}
__device__ __forceinline__ float sigm(float x) { return 1.f / (1.f + __expf(-x)); }
__device__ __forceinline__ float tanh_(float x) {
  float e = __expf(-2.f * fabsf(x));
  float t = (1.f - e) / (1.f + e);
  return x >= 0.f ? t : -t;
}
__device__ __forceinline__ void async16(const void* g, void* l) {
  __builtin_amdgcn_global_load_lds((const __attribute__((address_space(1))) void*)g,
                                   (__attribute__((address_space(3))) void*)l, 16, 0, 0);
}

// ---------------------------------------------------------------- init
__global__ void k_init(u16* hbuf, int* cnt) {
  int i = blockIdx.x * 256 + threadIdx.x;  // 64 blocks -> 16384 threads
  uint4 z = {0u, 0u, 0u, 0u};
  ((uint4*)hbuf)[i] = z;  // 2*64*1024 u16 = 262144 B = 16384 uint4
  if (i < T_) cnt[i] = 0;
}

// ---------------------------------------------------------------- x -> bf16
__global__ void k_cvt_x(const float4* __restrict__ x, ushort4* __restrict__ xb) {
  size_t i = (size_t)blockIdx.x * 256 + threadIdx.x;  // 8388608 float4s
  float4 v = x[i];
  ushort4 o;
  o.x = f2bf(v.x); o.y = f2bf(v.y); o.z = f2bf(v.z); o.w = f2bf(v.w);
  xb[i] = o;
}

// ---------------------------------------------------------------- W/U -> bf16, reordered
// Row r = w*32 + c, c = g*8 + jl; source row = {W,U}_g[w*8 + jl].
__global__ void k_cvt_w(const float* __restrict__ Wi, const float* __restrict__ Wf,
                        const float* __restrict__ Wo, const float* __restrict__ Wg,
                        const float* __restrict__ Ui, const float* __restrict__ Uf,
                        const float* __restrict__ Uo, const float* __restrict__ Ug,
                        u16* __restrict__ Wt, u16* __restrict__ Ut) {
  int idx = blockIdx.x * 256 + threadIdx.x;  // 4096 rows * 128 segs
  int r = idx >> 7;
  int s = idx & 127;
  int w = r >> 5, c = r & 31, g = c >> 3, jl = c & 7;
  int hrow = w * 8 + jl;
  const float* Wsrc = (g == 0) ? Wi : (g == 1) ? Wf : (g == 2) ? Wo : Wg;
  const float* Usrc = (g == 0) ? Ui : (g == 1) ? Uf : (g == 2) ? Uo : Ug;
  int so = hrow * 1024 + s * 8;
  int dovr = r * 1024 + s * 8;
  ushort4 a, b;
  a.x = f2bf(Wsrc[so + 0]); a.y = f2bf(Wsrc[so + 1]); a.z = f2bf(Wsrc[so + 2]); a.w = f2bf(Wsrc[so + 3]);
  b.x = f2bf(Wsrc[so + 4]); b.y = f2bf(Wsrc[so + 5]); b.z = f2bf(Wsrc[so + 6]); b.w = f2bf(Wsrc[so + 7]);
  *(ushort4*)&Wt[dovr] = a;
  *(ushort4*)&Wt[dovr + 4] = b;
  a.x = f2bf(Usrc[so + 0]); a.y = f2bf(Usrc[so + 1]); a.z = f2bf(Usrc[so + 2]); a.w = f2bf(Usrc[so + 3]);
  b.x = f2bf(Usrc[so + 4]); b.y = f2bf(Usrc[so + 5]); b.z = f2bf(Usrc[so + 6]); b.w = f2bf(Usrc[so + 7]);
  *(ushort4*)&Ut[dovr] = a;
  *(ushort4*)&Ut[dovr + 4] = b;
}

// ---------------------------------------------------------------- input GEMM
// xg(m, n) = sum_k xb[m][k] * Wt[n][k];  m = b*512 + t (== xb row), n = w*32+c.
// 128x128 tile, BK=32, 4 waves as 2x2, each wave 4x4 16x16x32 tiles.
// LDS layout [kq][row][8] so ds_read_b128 is 2-way-conflict-free and
// global_load_lds (uniform base + lane*16) stages it exactly.
__global__ __launch_bounds__(256) void k_gemm(const u16* __restrict__ xb,
                                              const u16* __restrict__ Wt,
                                              u16* __restrict__ xg) {
  __shared__ u16 As[4 * 128 * 8];
  __shared__ u16 Bs[4 * 128 * 8];
  const int tid = threadIdx.x;
  const int lane = tid & 63, wave = tid >> 6;
  const int wm = wave >> 1, wn = wave & 1;
  const int lr = lane & 15, lq = lane >> 4;
  const int m0 = blockIdx.y * 128, n0 = blockIdx.x * 128;

  f32x4 acc[4][4];
#pragma unroll
  for (int mt = 0; mt < 4; ++mt)
#pragma unroll
    for (int nt = 0; nt < 4; ++nt) acc[mt][nt] = {0.f, 0.f, 0.f, 0.f};

  for (int kk = 0; kk < 32; ++kk) {
    int k0 = kk * 32;
    __syncthreads();  // previous compute done before LDS overwrite
#pragma unroll
    for (int uu = 0; uu < 2; ++uu) {
      int u = wave * 2 + uu;        // 8 units: kq = u>>1, row-half = u&1
      int kq = u >> 1, rh = u & 1;
      int row = rh * 64 + lane;
      async16(&xb[(size_t)(m0 + row) * 1024 + k0 + kq * 8], &As[kq * 1024 + rh * 512]);
      async16(&Wt[(size_t)(n0 + row) * 1024 + k0 + kq * 8], &Bs[kq * 1024 + rh * 512]);
    }
    __syncthreads();  // staging complete (vmcnt drained by barrier)

    bf16x8 af[4], bfr[4];
#pragma unroll
    for (int mt = 0; mt < 4; ++mt)
      af[mt] = *(const bf16x8*)&As[lq * 1024 + (wm * 64 + mt * 16 + lr) * 8];
#pragma unroll
    for (int nt = 0; nt < 4; ++nt)
      bfr[nt] = *(const bf16x8*)&Bs[lq * 1024 + (wn * 64 + nt * 16 + lr) * 8];
#pragma unroll
    for (int mt = 0; mt < 4; ++mt)
#pragma unroll
      for (int nt = 0; nt < 4; ++nt)
        acc[mt][nt] = __builtin_amdgcn_mfma_f32_16x16x32_bf16(af[mt], bfr[nt], acc[mt][nt], 0, 0, 0);
  }

  // epilogue: C/D layout col=lane&15, row=(lane>>4)*4+reg
#pragma unroll
  for (int mt = 0; mt < 4; ++mt)
#pragma unroll
    for (int nt = 0; nt < 4; ++nt)
#pragma unroll
      for (int r = 0; r < 4; ++r) {
        int mg = m0 + wm * 64 + mt * 16 + lq * 4 + r;
        int ng = n0 + wn * 64 + nt * 16 + lr;
        int b = mg >> 9, t = mg & 511;
        int w = ng >> 5, c = ng & 31;
        xg[(size_t)t * (NWG * 2048) + w * 2048 + b * 32 + c] = f2bf(acc[mt][nt][r]);
      }
}

// ---------------------------------------------------------------- recurrence
// 128 WGs x 256 threads. WG w owns h-cols [8w, 8w+8) => 32 gate-cols.
// Wave = K-quarter; U fragments live in VGPRs for all 512 steps.
// Partials reduced through LDS; c-state in VGPRs; h broadcast via global
// double buffer + flag barrier (release fence -> atomicAdd -> acquire spin).
__global__ __launch_bounds__(256, 1) void k_lstm(
    const u16* __restrict__ Ut, const u16* __restrict__ xg, u16* hbuf, int* cnt,
    const float* __restrict__ bi, const float* __restrict__ bf_,
    const float* __restrict__ bo, const float* __restrict__ bg,
    float* __restrict__ out) {
  __shared__ float P[4 * 64 * 33];  // [wave][m][c], stride 33 kills bank conflicts
  const int tid = threadIdx.x;
  const int lane = tid & 63, wave = tid >> 6;
  const int lr = lane & 15, lq = lane >> 4;
  const int w = blockIdx.x;

  // U fragments: B[n = lane&15][k = (lane>>4)*8 + j], n relative to tile base.
  bf16x8 Bf[2][8];
#pragma unroll
  for (int nt = 0; nt < 2; ++nt)
#pragma unroll
    for (int ks = 0; ks < 8; ++ks) {
      int n = w * 32 + nt * 16 + lr;
      int k = wave * 256 + ks * 32 + lq * 8;
      Bf[nt][ks] = *(const bf16x8*)&Ut[(size_t)n * 1024 + k];
    }

  // elementwise ownership: m = wave*16 + lr, j = lq*2 + p (p=0,1)
  const int em = wave * 16 + lr;
  float bia[2][4];
#pragma unroll
  for (int p = 0; p < 2; ++p) {
    int hc = w * 8 + lq * 2 + p;
    bia[p][0] = bi[hc]; bia[p][1] = bf_[hc]; bia[p][2] = bo[hc]; bia[p][3] = bg[hc];
  }
  float cst0 = 0.f, cst1 = 0.f;

  for (int t = 0; t < T_; ++t) {
    const u16* hin = hbuf + (size_t)(t & 1) * (B_ * H_);
    u16* hout = hbuf + (size_t)((t + 1) & 1) * (B_ * H_);

    // xg slice loads (issued early; used after MFMA loop -> latency hidden)
    const u16* xgp = xg + (size_t)t * (NWG * 2048) + w * 2048;
    u16 xv[2][4];
#pragma unroll
    for (int p = 0; p < 2; ++p)
#pragma unroll
      for (int g = 0; g < 4; ++g)
        xv[p][g] = xgp[em * 32 + g * 8 + lq * 2 + p];

    f32x4 acc[4][2];
#pragma unroll
    for (int mt = 0; mt < 4; ++mt) { acc[mt][0] = {0.f,0.f,0.f,0.f}; acc[mt][1] = {0.f,0.f,0.f,0.f}; }

#pragma unroll
    for (int ks = 0; ks < 8; ++ks) {
      int k = wave * 256 + ks * 32 + lq * 8;
      bf16x8 af[4];
#pragma unroll
      for (int mt = 0; mt < 4; ++mt)
        af[mt] = *(const bf16x8*)&hin[(size_t)(mt * 16 + lr) * 1024 + k];
#pragma unroll
      for (int mt = 0; mt < 4; ++mt) {
        acc[mt][0] = __builtin_amdgcn_mfma_f32_16x16x32_bf16(af[mt], Bf[0][ks], acc[mt][0], 0, 0, 0);
        acc[mt][1] = __builtin_amdgcn_mfma_f32_16x16x32_bf16(af[mt], Bf[1][ks], acc[mt][1], 0, 0, 0);
      }
    }

    // dump partials (K-split across waves) to LDS
#pragma unroll
    for (int mt = 0; mt < 4; ++mt)
#pragma unroll
      for (int nt = 0; nt < 2; ++nt)
#pragma unroll
        for (int r = 0; r < 4; ++r) {
          int m = mt * 16 + lq * 4 + r;
          int c = nt * 16 + lr;
          P[(wave * 64 + m) * 33 + c] = acc[mt][nt][r];
        }
    __syncthreads();

    float hv[2];
#pragma unroll
    for (int p = 0; p < 2; ++p) {
      int j = lq * 2 + p;
      float pre[4];
#pragma unroll
      for (int g = 0; g < 4; ++g) {
        int c = g * 8 + j;
        float s = P[(0 * 64 + em) * 33 + c] + P[(1 * 64 + em) * 33 + c] +
                  P[(2 * 64 + em) * 33 + c] + P[(3 * 64 + em) * 33 + c];
        pre[g] = s + bf2f(xv[p][g]) + bia[p][g];
      }
      float iv = sigm(pre[0]);
      float fv = sigm(pre[1]);
      float ov = sigm(pre[2]);
      float gv = tanh_(pre[3]);
      float cn = fv * (p == 0 ? cst0 : cst1) + iv * gv;
      if (p == 0) cst0 = cn; else cst1 = cn;
      hv[p] = ov * tanh_(cn);
    }

    int hc0 = w * 8 + lq * 2;
    ushort2 hb2; hb2.x = f2bf(hv[0]); hb2.y = f2bf(hv[1]);
    *(ushort2*)&hout[em * 1024 + hc0] = hb2;
    float2 f2v; f2v.x = hv[0]; f2v.y = hv[1];
    *(float2*)&out[((size_t)em * 512 + t) * 1024 + hc0] = f2v;
    if (t == T_ - 1) {
      *(float2*)&out[(size_t)BTH + em * 1024 + hc0] = f2v;              // h_last
      float2 c2v; c2v.x = cst0; c2v.y = cst1;
      *(float2*)&out[(size_t)BTH + B_ * H_ + em * 1024 + hc0] = c2v;    // c_last
    }

    if (t < T_ - 1) {
      __syncthreads();  // all WG stores drained (vmcnt 0 before s_barrier)
      if (tid == 0) {
        __builtin_amdgcn_fence(__ATOMIC_RELEASE, "agent");  // wb XCD L2 -> LLC
        atomicAdd(&cnt[t], 1);
        while (__hip_atomic_load(&cnt[t], __ATOMIC_ACQUIRE, __HIP_MEMORY_SCOPE_AGENT) < NWG)
          __builtin_amdgcn_s_sleep(1);
      }
      __syncthreads();
      __builtin_amdgcn_fence(__ATOMIC_ACQUIRE, "agent");  // inv stale L1/L2 lines
    }
  }
}

// ---------------------------------------------------------------- launch
extern "C" void kernel_launch(void* const* d_in, const int* in_sizes, int n_in,
                              void* d_out, int out_size, void* d_ws, size_t ws_size,
                              hipStream_t stream) {
  const float* x  = (const float*)d_in[0];
  const float* Wi = (const float*)d_in[1];
  const float* Wf = (const float*)d_in[2];
  const float* Wo = (const float*)d_in[3];
  const float* Wg = (const float*)d_in[4];
  const float* Ui = (const float*)d_in[5];
  const float* Uf = (const float*)d_in[6];
  const float* Uo = (const float*)d_in[7];
  const float* Ug = (const float*)d_in[8];
  const float* bi = (const float*)d_in[9];
  const float* bf = (const float*)d_in[10];
  const float* bo = (const float*)d_in[11];
  const float* bg = (const float*)d_in[12];
  float* out = (float*)d_out;

  char* ws = (char*)d_ws;
  u16* xb   = (u16*)(ws + OFF_XB);
  u16* Wt   = (u16*)(ws + OFF_WT);
  u16* Ut   = (u16*)(ws + OFF_UT);
  u16* xg   = (u16*)(ws + OFF_XG);
  u16* hbuf = (u16*)(ws + OFF_HB);
  int* cnt  = (int*)(ws + OFF_CNT);

  k_init<<<64, 256, 0, stream>>>(hbuf, cnt);
  k_cvt_x<<<32768, 256, 0, stream>>>((const float4*)x, (ushort4*)xb);
  k_cvt_w<<<2048, 256, 0, stream>>>(Wi, Wf, Wo, Wg, Ui, Uf, Uo, Ug, Wt, Ut);
  k_gemm<<<dim3(32, 256), 256, 0, stream>>>(xb, Wt, xg);
  k_lstm<<<NWG, 256, 0, stream>>>(Ut, xg, hbuf, cnt, bi, bf, bo, bg, out);
}

// Round 2
// 7498.737 us; speedup vs baseline: 1.2167x; 1.2167x over previous
//
#include <hip/hip_runtime.h>
#include <stdint.h>
#include <stddef.h>

// LSTM: B=64, T=512, I=H=1024. fp32 in/out, bf16 MFMA compute internally.
//
// Pipeline (all on `stream`):
//   k_init    : zero h double-buffer + per-WG flags
//   k_cvt_x   : x fp32 -> bf16
//   k_cvt_w   : W*/U* fp32 -> bf16, rows reordered to (wg, gate, local-col)
//   k_gemm    : xg[t][wg][b][c] = x @ Wcat^T   (m97-style 128x128 bf16 GEMM)
//   k_lstm    : persistent 128-WG recurrence; U in VGPRs, c in VGPRs.
//               Per-step sync: sc1 write-through h stores + per-WG monotone
//               flags + relaxed sc1 poll + ONE acquire fence (buffer_inv).
//               (R1 lesson: release-fence wbl2 + acquire-spin inv storm was
//               16 us/step; this protocol has no wbl2 and one inv/step.)

typedef unsigned short u16;
typedef unsigned int u32;
typedef short bf16x8 __attribute__((ext_vector_type(8)));
typedef float f32x4 __attribute__((ext_vector_type(4)));

#define B_ 64
#define T_ 512
#define I_ 1024
#define H_ 1024
#define NWG 128
#define BTH (B_ * T_ * H_)

// ws layout (bytes)
#define OFF_XB 0UL                 // 64 MB  : x bf16 [64][512][1024]
#define OFF_WT 67108864UL          // 8 MB   : Wcat bf16, reordered rows [4096][1024]
#define OFF_UT 75497472UL          // 8 MB   : Ucat bf16, reordered rows [4096][1024]
#define OFF_XG 83886080UL          // 256 MB : xg bf16 [512][128][64][32]
#define OFF_HB 352321536UL         // 256 KB : h double buffer bf16 2x[64][1024]
#define OFF_FLG 352583680UL        // flags int[128] (monotone step counters)

__device__ __forceinline__ u16 f2bf(float f) {
  u32 u = __builtin_bit_cast(u32, f);
  return (u16)((u + 0x7FFFu + ((u >> 16) & 1u)) >> 16);
}
__device__ __forceinline__ float bf2f(u16 h) {
  u32 u = ((u32)h) << 16;
  return __builtin_bit_cast(float, u);
}
__device__ __forceinline__ float sigm(float x) { return 1.f / (1.f + __expf(-x)); }
__device__ __forceinline__ float tanh_(float x) {
  float e = __expf(-2.f * fabsf(x));
  float t = (1.f - e) / (1.f + e);
  return x >= 0.f ? t : -t;
}
__device__ __forceinline__ void async16(const void* g, void* l) {
  __builtin_amdgcn_global_load_lds((const __attribute__((address_space(1))) void*)g,
                                   (__attribute__((address_space(3))) void*)l, 16, 0, 0);
}
// Agent-visible (LLC write-through) store / load — bypass XCD L2 so no
// wbl2/inv cache ops are needed for cross-WG visibility.
__device__ __forceinline__ void st_u32_sc1(u32* p, u32 v) {
  asm volatile("global_store_dword %0, %1, off sc1" : : "v"(p), "v"(v) : "memory");
}
__device__ __forceinline__ u32 ld_u32_sc1(const u32* p) {
  u32 r;
  asm volatile("global_load_dword %0, %1, off sc1\n\ts_waitcnt vmcnt(0)"
               : "=v"(r) : "v"(p) : "memory");
  return r;
}
__device__ __forceinline__ void waitcnt_vm0() {
  asm volatile("s_waitcnt vmcnt(0)" ::: "memory");
}

// ---------------------------------------------------------------- init
__global__ void k_init(u16* hbuf, u32* flg) {
  int i = blockIdx.x * 256 + threadIdx.x;  // 64 blocks -> 16384 threads
  uint4 z = {0u, 0u, 0u, 0u};
  ((uint4*)hbuf)[i] = z;  // 2*64*1024 u16 = 262144 B = 16384 uint4
  if (i < NWG) flg[i] = 0u;
}

// ---------------------------------------------------------------- x -> bf16
__global__ void k_cvt_x(const float4* __restrict__ x, ushort4* __restrict__ xb) {
  size_t i = (size_t)blockIdx.x * 256 + threadIdx.x;  // 8388608 float4s
  float4 v = x[i];
  ushort4 o;
  o.x = f2bf(v.x); o.y = f2bf(v.y); o.z = f2bf(v.z); o.w = f2bf(v.w);
  xb[i] = o;
}

// ---------------------------------------------------------------- W/U -> bf16, reordered
__global__ void k_cvt_w(const float* __restrict__ Wi, const float* __restrict__ Wf,
                        const float* __restrict__ Wo, const float* __restrict__ Wg,
                        const float* __restrict__ Ui, const float* __restrict__ Uf,
                        const float* __restrict__ Uo, const float* __restrict__ Ug,
                        u16* __restrict__ Wt, u16* __restrict__ Ut) {
  int idx = blockIdx.x * 256 + threadIdx.x;  // 4096 rows * 128 segs
  int r = idx >> 7;
  int s = idx & 127;
  int w = r >> 5, c = r & 31, g = c >> 3, jl = c & 7;
  int hrow = w * 8 + jl;
  const float* Wsrc = (g == 0) ? Wi : (g == 1) ? Wf : (g == 2) ? Wo : Wg;
  const float* Usrc = (g == 0) ? Ui : (g == 1) ? Uf : (g == 2) ? Uo : Ug;
  int so = hrow * 1024 + s * 8;
  int dovr = r * 1024 + s * 8;
  ushort4 a, b;
  a.x = f2bf(Wsrc[so + 0]); a.y = f2bf(Wsrc[so + 1]); a.z = f2bf(Wsrc[so + 2]); a.w = f2bf(Wsrc[so + 3]);
  b.x = f2bf(Wsrc[so + 4]); b.y = f2bf(Wsrc[so + 5]); b.z = f2bf(Wsrc[so + 6]); b.w = f2bf(Wsrc[so + 7]);
  *(ushort4*)&Wt[dovr] = a;
  *(ushort4*)&Wt[dovr + 4] = b;
  a.x = f2bf(Usrc[so + 0]); a.y = f2bf(Usrc[so + 1]); a.z = f2bf(Usrc[so + 2]); a.w = f2bf(Usrc[so + 3]);
  b.x = f2bf(Usrc[so + 4]); b.y = f2bf(Usrc[so + 5]); b.z = f2bf(Usrc[so + 6]); b.w = f2bf(Usrc[so + 7]);
  *(ushort4*)&Ut[dovr] = a;
  *(ushort4*)&Ut[dovr + 4] = b;
}

// ---------------------------------------------------------------- input GEMM
__global__ __launch_bounds__(256) void k_gemm(const u16* __restrict__ xb,
                                              const u16* __restrict__ Wt,
                                              u16* __restrict__ xg) {
  __shared__ u16 As[4 * 128 * 8];
  __shared__ u16 Bs[4 * 128 * 8];
  const int tid = threadIdx.x;
  const int lane = tid & 63, wave = tid >> 6;
  const int wm = wave >> 1, wn = wave & 1;
  const int lr = lane & 15, lq = lane >> 4;
  const int m0 = blockIdx.y * 128, n0 = blockIdx.x * 128;

  f32x4 acc[4][4];
#pragma unroll
  for (int mt = 0; mt < 4; ++mt)
#pragma unroll
    for (int nt = 0; nt < 4; ++nt) acc[mt][nt] = {0.f, 0.f, 0.f, 0.f};

  for (int kk = 0; kk < 32; ++kk) {
    int k0 = kk * 32;
    __syncthreads();
#pragma unroll
    for (int uu = 0; uu < 2; ++uu) {
      int u = wave * 2 + uu;
      int kq = u >> 1, rh = u & 1;
      int row = rh * 64 + lane;
      async16(&xb[(size_t)(m0 + row) * 1024 + k0 + kq * 8], &As[kq * 1024 + rh * 512]);
      async16(&Wt[(size_t)(n0 + row) * 1024 + k0 + kq * 8], &Bs[kq * 1024 + rh * 512]);
    }
    __syncthreads();

    bf16x8 af[4], bfr[4];
#pragma unroll
    for (int mt = 0; mt < 4; ++mt)
      af[mt] = *(const bf16x8*)&As[lq * 1024 + (wm * 64 + mt * 16 + lr) * 8];
#pragma unroll
    for (int nt = 0; nt < 4; ++nt)
      bfr[nt] = *(const bf16x8*)&Bs[lq * 1024 + (wn * 64 + nt * 16 + lr) * 8];
#pragma unroll
    for (int mt = 0; mt < 4; ++mt)
#pragma unroll
      for (int nt = 0; nt < 4; ++nt)
        acc[mt][nt] = __builtin_amdgcn_mfma_f32_16x16x32_bf16(af[mt], bfr[nt], acc[mt][nt], 0, 0, 0);
  }

#pragma unroll
  for (int mt = 0; mt < 4; ++mt)
#pragma unroll
    for (int nt = 0; nt < 4; ++nt)
#pragma unroll
      for (int r = 0; r < 4; ++r) {
        int mg = m0 + wm * 64 + mt * 16 + lq * 4 + r;
        int ng = n0 + wn * 64 + nt * 16 + lr;
        int b = mg >> 9, t = mg & 511;
        int w = ng >> 5, c = ng & 31;
        xg[(size_t)t * (NWG * 2048) + w * 2048 + b * 32 + c] = f2bf(acc[mt][nt][r]);
      }
}

// ---------------------------------------------------------------- recurrence
__global__ __launch_bounds__(256, 1) void k_lstm(
    const u16* __restrict__ Ut, const u16* __restrict__ xg, u16* hbuf, u32* flg,
    const float* __restrict__ bi, const float* __restrict__ bf_,
    const float* __restrict__ bo, const float* __restrict__ bg,
    float* __restrict__ out) {
  __shared__ float P[4 * 64 * 33];
  const int tid = threadIdx.x;
  const int lane = tid & 63, wave = tid >> 6;
  const int lr = lane & 15, lq = lane >> 4;
  const int w = blockIdx.x;

  // U fragments live in VGPRs for all 512 steps.
  bf16x8 Bf[2][8];
#pragma unroll
  for (int nt = 0; nt < 2; ++nt)
#pragma unroll
    for (int ks = 0; ks < 8; ++ks) {
      int n = w * 32 + nt * 16 + lr;
      int k = wave * 256 + ks * 32 + lq * 8;
      Bf[nt][ks] = *(const bf16x8*)&Ut[(size_t)n * 1024 + k];
    }

  const int em = wave * 16 + lr;  // elementwise batch row
  float bia[2][4];
#pragma unroll
  for (int p = 0; p < 2; ++p) {
    int hc = w * 8 + lq * 2 + p;
    bia[p][0] = bi[hc]; bia[p][1] = bf_[hc]; bia[p][2] = bo[hc]; bia[p][3] = bg[hc];
  }
  float cst0 = 0.f, cst1 = 0.f;

  for (int t = 0; t < T_; ++t) {
    const u16* hin = hbuf + (size_t)(t & 1) * (B_ * H_);
    u16* hout = hbuf + (size_t)((t + 1) & 1) * (B_ * H_);

    // xg slice: 4 dword loads (pairs j = lq*2, lq*2+1 are adjacent)
    const u16* xgp = xg + (size_t)t * (NWG * 2048) + w * 2048;
    u32 xv[4];
#pragma unroll
    for (int g = 0; g < 4; ++g)
      xv[g] = *(const u32*)&xgp[em * 32 + g * 8 + lq * 2];

    f32x4 acc[4][2];
#pragma unroll
    for (int mt = 0; mt < 4; ++mt) { acc[mt][0] = {0.f,0.f,0.f,0.f}; acc[mt][1] = {0.f,0.f,0.f,0.f}; }

#pragma unroll
    for (int ks = 0; ks < 8; ++ks) {
      int k = wave * 256 + ks * 32 + lq * 8;
      bf16x8 af[4];
#pragma unroll
      for (int mt = 0; mt < 4; ++mt)
        af[mt] = *(const bf16x8*)&hin[(size_t)(mt * 16 + lr) * 1024 + k];
#pragma unroll
      for (int mt = 0; mt < 4; ++mt) {
        acc[mt][0] = __builtin_amdgcn_mfma_f32_16x16x32_bf16(af[mt], Bf[0][ks], acc[mt][0], 0, 0, 0);
        acc[mt][1] = __builtin_amdgcn_mfma_f32_16x16x32_bf16(af[mt], Bf[1][ks], acc[mt][1], 0, 0, 0);
      }
    }

    // K-split partials -> LDS
#pragma unroll
    for (int mt = 0; mt < 4; ++mt)
#pragma unroll
      for (int nt = 0; nt < 2; ++nt)
#pragma unroll
        for (int r = 0; r < 4; ++r) {
          int m = mt * 16 + lq * 4 + r;
          int c = nt * 16 + lr;
          P[(wave * 64 + m) * 33 + c] = acc[mt][nt][r];
        }
    __syncthreads();

    float hv[2];
#pragma unroll
    for (int p = 0; p < 2; ++p) {
      int j = lq * 2 + p;
      float pre[4];
#pragma unroll
      for (int g = 0; g < 4; ++g) {
        int c = g * 8 + j;
        float s = P[(0 * 64 + em) * 33 + c] + P[(1 * 64 + em) * 33 + c] +
                  P[(2 * 64 + em) * 33 + c] + P[(3 * 64 + em) * 33 + c];
        u16 xh = (u16)(p == 0 ? (xv[g] & 0xFFFFu) : (xv[g] >> 16));
        pre[g] = s + bf2f(xh) + bia[p][g];
      }
      float iv = sigm(pre[0]);
      float fv = sigm(pre[1]);
      float ov = sigm(pre[2]);
      float gv = tanh_(pre[3]);
      float cn = fv * (p == 0 ? cst0 : cst1) + iv * gv;
      if (p == 0) cst0 = cn; else cst1 = cn;
      hv[p] = ov * tanh_(cn);
    }

    int hc0 = w * 8 + lq * 2;
    // h broadcast: write-through to LLC (sc1) — no release fence needed.
    u32 hpack = (u32)f2bf(hv[0]) | ((u32)f2bf(hv[1]) << 16);
    st_u32_sc1((u32*)&hout[em * 1024 + hc0], hpack);
    float2 f2v; f2v.x = hv[0]; f2v.y = hv[1];
    *(float2*)&out[((size_t)em * 512 + t) * 1024 + hc0] = f2v;
    if (t == T_ - 1) {
      *(float2*)&out[(size_t)BTH + em * 1024 + hc0] = f2v;              // h_last
      float2 c2v; c2v.x = cst0; c2v.y = cst1;
      *(float2*)&out[(size_t)BTH + B_ * H_ + em * 1024 + hc0] = c2v;    // c_last
    }

    if (t < T_ - 1) {
      waitcnt_vm0();      // h stores ack'd at LLC before flag
      __syncthreads();    // all waves drained
      if (tid == 0) st_u32_sc1(&flg[w], (u32)(t + 1));
      if (wave == 0) {    // vector poll: 64 lanes x 2 flags, relaxed sc1
        const u32* f0p = flg + lane;
        const u32* f1p = flg + 64 + lane;
        for (;;) {
          u32 a = ld_u32_sc1(f0p);
          u32 b = ld_u32_sc1(f1p);
          if (__ballot(a > (u32)t && b > (u32)t) == ~0ull) break;
          __builtin_amdgcn_s_sleep(1);
        }
      }
      __syncthreads();
      // one inv/step so plain (L2-cached) h loads see fresh data
      __builtin_amdgcn_fence(__ATOMIC_ACQUIRE, "agent");
    }
  }
}

// ---------------------------------------------------------------- launch
extern "C" void kernel_launch(void* const* d_in, const int* in_sizes, int n_in,
                              void* d_out, int out_size, void* d_ws, size_t ws_size,
                              hipStream_t stream) {
  const float* x  = (const float*)d_in[0];
  const float* Wi = (const float*)d_in[1];
  const float* Wf = (const float*)d_in[2];
  const float* Wo = (const float*)d_in[3];
  const float* Wg = (const float*)d_in[4];
  const float* Ui = (const float*)d_in[5];
  const float* Uf = (const float*)d_in[6];
  const float* Uo = (const float*)d_in[7];
  const float* Ug = (const float*)d_in[8];
  const float* bi = (const float*)d_in[9];
  const float* bf = (const float*)d_in[10];
  const float* bo = (const float*)d_in[11];
  const float* bg = (const float*)d_in[12];
  float* out = (float*)d_out;

  char* ws = (char*)d_ws;
  u16* xb   = (u16*)(ws + OFF_XB);
  u16* Wt   = (u16*)(ws + OFF_WT);
  u16* Ut   = (u16*)(ws + OFF_UT);
  u16* xg   = (u16*)(ws + OFF_XG);
  u16* hbuf = (u16*)(ws + OFF_HB);
  u32* flg  = (u32*)(ws + OFF_FLG);

  k_init<<<64, 256, 0, stream>>>(hbuf, flg);
  k_cvt_x<<<32768, 256, 0, stream>>>((const float4*)x, (ushort4*)xb);
  k_cvt_w<<<2048, 256, 0, stream>>>(Wi, Wf, Wo, Wg, Ui, Uf, Uo, Ug, Wt, Ut);
  k_gemm<<<dim3(32, 256), 256, 0, stream>>>(xb, Wt, xg);
  k_lstm<<<NWG, 256, 0, stream>>>(Ut, xg, hbuf, flg, bi, bf, bo, bg, out);
}

// Round 3
// 5764.941 us; speedup vs baseline: 1.5826x; 1.3007x over previous
//
#include <hip/hip_runtime.h>
#include <stdint.h>
#include <stddef.h>

// LSTM: B=64, T=512, I=H=1024. fp32 in/out, bf16 MFMA compute internally.
//
//   k_init    : zero h double-buffer + per-WG flags
//   k_cvt_x   : x fp32 -> bf16
//   k_cvt_w   : W*/U* fp32 -> bf16, rows reordered to (wg64, gate, local-col)
//   k_gemm    : xg = x @ Wcat^T (m97-style 128x128 bf16 GEMM), xg[t][w][b][c]
//   k_lstm    : persistent 64-WG x 512-thread recurrence.
//               h exchanged in granule-major global layout h_g[k/8][b][8];
//               staged to LDS via contiguous global_load_lds dwordx4;
//               U in VGPRs; c in VGPRs; P-reduce LDS aliased over h-LDS;
//               sync = sc1 h stores + 64 monotone flags + 1-load poll +
//               one acquire fence (buffer_inv) per step.

typedef unsigned short u16;
typedef unsigned int u32;
typedef short bf16x8 __attribute__((ext_vector_type(8)));
typedef float f32x4 __attribute__((ext_vector_type(4)));

#define B_ 64
#define T_ 512
#define I_ 1024
#define H_ 1024
#define NWG 64
#define BTH (B_ * T_ * H_)

// ws layout (bytes)
#define OFF_XB 0UL                 // 64 MB  : x bf16 [64][512][1024]
#define OFF_WT 67108864UL          // 8 MB   : Wcat bf16, reordered [4096][1024]
#define OFF_UT 75497472UL          // 8 MB   : Ucat bf16, reordered [4096][1024]
#define OFF_XG 83886080UL          // 256 MB : xg bf16 [512][64][64][64]
#define OFF_HB 352321536UL         // 256 KB : h dbuf, granule layout 2x[128][64][8]
#define OFF_FLG 352583680UL        // flags u32[64]

__device__ __forceinline__ u16 f2bf(float f) {
  u32 u = __builtin_bit_cast(u32, f);
  return (u16)((u + 0x7FFFu + ((u >> 16) & 1u)) >> 16);
}
__device__ __forceinline__ float bf2f(u16 h) {
  u32 u = ((u32)h) << 16;
  return __builtin_bit_cast(float, u);
}
__device__ __forceinline__ float sigm(float x) { return 1.f / (1.f + __expf(-x)); }
__device__ __forceinline__ float tanh_(float x) {
  float e = __expf(-2.f * fabsf(x));
  float t = (1.f - e) / (1.f + e);
  return x >= 0.f ? t : -t;
}
__device__ __forceinline__ void async16(const void* g, void* l) {
  __builtin_amdgcn_global_load_lds((const __attribute__((address_space(1))) void*)g,
                                   (__attribute__((address_space(3))) void*)l, 16, 0, 0);
}
__device__ __forceinline__ void st_u32_sc1(u32* p, u32 v) {
  asm volatile("global_store_dword %0, %1, off sc1" : : "v"(p), "v"(v) : "memory");
}
__device__ __forceinline__ u32 ld_u32_sc1(const u32* p) {
  u32 r;
  asm volatile("global_load_dword %0, %1, off sc1\n\ts_waitcnt vmcnt(0)"
               : "=v"(r) : "v"(p) : "memory");
  return r;
}
__device__ __forceinline__ void waitcnt_vm0() {
  asm volatile("s_waitcnt vmcnt(0)" ::: "memory");
}

// ---------------------------------------------------------------- init
__global__ void k_init(u16* hbuf, u32* flg) {
  int i = blockIdx.x * 256 + threadIdx.x;  // 64 blocks -> 16384 threads
  uint4 z = {0u, 0u, 0u, 0u};
  ((uint4*)hbuf)[i] = z;  // 2*128*64*8 u16 = 262144 B = 16384 uint4
  if (i < NWG) flg[i] = 0u;
}

// ---------------------------------------------------------------- x -> bf16
__global__ void k_cvt_x(const float4* __restrict__ x, ushort4* __restrict__ xb) {
  size_t i = (size_t)blockIdx.x * 256 + threadIdx.x;  // 8388608 float4s
  float4 v = x[i];
  ushort4 o;
  o.x = f2bf(v.x); o.y = f2bf(v.y); o.z = f2bf(v.z); o.w = f2bf(v.w);
  xb[i] = o;
}

// ---------------------------------------------------------------- W/U -> bf16, reordered
// Row r = w*64 + c, c = g*16 + jl; source row = {W,U}_g[w*16 + jl].
__global__ void k_cvt_w(const float* __restrict__ Wi, const float* __restrict__ Wf,
                        const float* __restrict__ Wo, const float* __restrict__ Wg,
                        const float* __restrict__ Ui, const float* __restrict__ Uf,
                        const float* __restrict__ Uo, const float* __restrict__ Ug,
                        u16* __restrict__ Wt, u16* __restrict__ Ut) {
  int idx = blockIdx.x * 256 + threadIdx.x;  // 4096 rows * 128 segs
  int r = idx >> 7;
  int s = idx & 127;
  int w = r >> 6, c = r & 63, g = c >> 4, jl = c & 15;
  int hrow = w * 16 + jl;
  const float* Wsrc = (g == 0) ? Wi : (g == 1) ? Wf : (g == 2) ? Wo : Wg;
  const float* Usrc = (g == 0) ? Ui : (g == 1) ? Uf : (g == 2) ? Uo : Ug;
  int so = hrow * 1024 + s * 8;
  int dovr = r * 1024 + s * 8;
  ushort4 a, b;
  a.x = f2bf(Wsrc[so + 0]); a.y = f2bf(Wsrc[so + 1]); a.z = f2bf(Wsrc[so + 2]); a.w = f2bf(Wsrc[so + 3]);
  b.x = f2bf(Wsrc[so + 4]); b.y = f2bf(Wsrc[so + 5]); b.z = f2bf(Wsrc[so + 6]); b.w = f2bf(Wsrc[so + 7]);
  *(ushort4*)&Wt[dovr] = a;
  *(ushort4*)&Wt[dovr + 4] = b;
  a.x = f2bf(Usrc[so + 0]); a.y = f2bf(Usrc[so + 1]); a.z = f2bf(Usrc[so + 2]); a.w = f2bf(Usrc[so + 3]);
  b.x = f2bf(Usrc[so + 4]); b.y = f2bf(Usrc[so + 5]); b.z = f2bf(Usrc[so + 6]); b.w = f2bf(Usrc[so + 7]);
  *(ushort4*)&Ut[dovr] = a;
  *(ushort4*)&Ut[dovr + 4] = b;
}

// ---------------------------------------------------------------- input GEMM
__global__ __launch_bounds__(256) void k_gemm(const u16* __restrict__ xb,
                                              const u16* __restrict__ Wt,
                                              u16* __restrict__ xg) {
  __shared__ u16 As[4 * 128 * 8];
  __shared__ u16 Bs[4 * 128 * 8];
  const int tid = threadIdx.x;
  const int lane = tid & 63, wave = tid >> 6;
  const int wm = wave >> 1, wn = wave & 1;
  const int lr = lane & 15, lq = lane >> 4;
  const int m0 = blockIdx.y * 128, n0 = blockIdx.x * 128;

  f32x4 acc[4][4];
#pragma unroll
  for (int mt = 0; mt < 4; ++mt)
#pragma unroll
    for (int nt = 0; nt < 4; ++nt) acc[mt][nt] = {0.f, 0.f, 0.f, 0.f};

  for (int kk = 0; kk < 32; ++kk) {
    int k0 = kk * 32;
    __syncthreads();
#pragma unroll
    for (int uu = 0; uu < 2; ++uu) {
      int u = wave * 2 + uu;
      int kq = u >> 1, rh = u & 1;
      int row = rh * 64 + lane;
      async16(&xb[(size_t)(m0 + row) * 1024 + k0 + kq * 8], &As[kq * 1024 + rh * 512]);
      async16(&Wt[(size_t)(n0 + row) * 1024 + k0 + kq * 8], &Bs[kq * 1024 + rh * 512]);
    }
    __syncthreads();

    bf16x8 af[4], bfr[4];
#pragma unroll
    for (int mt = 0; mt < 4; ++mt)
      af[mt] = *(const bf16x8*)&As[lq * 1024 + (wm * 64 + mt * 16 + lr) * 8];
#pragma unroll
    for (int nt = 0; nt < 4; ++nt)
      bfr[nt] = *(const bf16x8*)&Bs[lq * 1024 + (wn * 64 + nt * 16 + lr) * 8];
#pragma unroll
    for (int mt = 0; mt < 4; ++mt)
#pragma unroll
      for (int nt = 0; nt < 4; ++nt)
        acc[mt][nt] = __builtin_amdgcn_mfma_f32_16x16x32_bf16(af[mt], bfr[nt], acc[mt][nt], 0, 0, 0);
  }

#pragma unroll
  for (int mt = 0; mt < 4; ++mt)
#pragma unroll
    for (int nt = 0; nt < 4; ++nt)
#pragma unroll
      for (int r = 0; r < 4; ++r) {
        int mg = m0 + wm * 64 + mt * 16 + lq * 4 + r;
        int ngl = n0 + wn * 64 + nt * 16 + lr;
        int b = mg >> 9, t = mg & 511;
        int w = ngl >> 6, c = ngl & 63;
        xg[(size_t)t * 262144 + w * 4096 + b * 64 + c] = f2bf(acc[mt][nt][r]);
      }
}

// ---------------------------------------------------------------- recurrence
// 64 WGs x 512 threads (8 waves = 4 kq x 2 ng). WG w owns gate cols
// [64w, 64w+64) => h cols [16w, 16w+16). Full h staged to LDS per step.
__global__ __launch_bounds__(512, 2) void k_lstm(
    const u16* __restrict__ Ut, const u16* __restrict__ xg, u16* hbuf, u32* flg,
    const float* __restrict__ bi, const float* __restrict__ bf_,
    const float* __restrict__ bo, const float* __restrict__ bg,
    float* __restrict__ out) {
  __shared__ __align__(16) unsigned char LDSB[131072];
  u16* hL = (u16*)LDSB;    // h staged: [granule 128][b 64][8 u16]
  float* P = (float*)LDSB; // aliased after MFMA: [ng 2][kq 4][b 64][34]

  const int tid = threadIdx.x;
  const int lane = tid & 63, wave = tid >> 6;
  const int lr = lane & 15, lq = lane >> 4;
  const int kq = wave >> 1, ng = wave & 1;
  const int w = blockIdx.x;

  // U fragments resident in VGPRs for all 512 steps.
  bf16x8 Bf[2][8];
#pragma unroll
  for (int nt = 0; nt < 2; ++nt)
#pragma unroll
    for (int ks = 0; ks < 8; ++ks) {
      int n = w * 64 + ng * 32 + nt * 16 + lr;
      int k = kq * 256 + ks * 32 + lq * 8;
      Bf[nt][ks] = *(const bf16x8*)&Ut[(size_t)n * 1024 + k];
    }

  // elementwise ownership: batch b = lane, q = wave -> jl = 2q, 2q+1
  const int q = wave, b = lane;
  float bia[2][4];
#pragma unroll
  for (int p = 0; p < 2; ++p) {
    int hc = w * 16 + q * 2 + p;
    bia[p][0] = bi[hc]; bia[p][1] = bf_[hc]; bia[p][2] = bo[hc]; bia[p][3] = bg[hc];
  }
  float cst0 = 0.f, cst1 = 0.f;
  const int Gh = w * 2 + (q >> 2);     // output granule
  const int c8 = (q * 2) & 7;          // position within granule

  for (int t = 0; t < T_; ++t) {
    const u16* hin = hbuf + (size_t)(t & 1) * 65536;

    // stage full h (128 KB) to LDS: 16 contiguous-1KB async ops per wave
    {
      int G0 = kq * 32 + ng * 16;
#pragma unroll
      for (int it = 0; it < 16; ++it) {
        int G = G0 + it;
        async16(&hin[(size_t)(G * 64 + lane) * 8], (char*)LDSB + G * 1024);
      }
    }
    // xg slice loads (used in elementwise; latency hidden behind MFMA)
    const u16* xgp = xg + (size_t)t * 262144 + w * 4096;
    u32 xv[4];
#pragma unroll
    for (int g = 0; g < 4; ++g)
      xv[g] = *(const u32*)&xgp[b * 64 + g * 16 + q * 2];

    __syncthreads();  // staging complete (vmcnt drained before barrier)

    f32x4 acc[4][2];
#pragma unroll
    for (int mt = 0; mt < 4; ++mt) { acc[mt][0] = {0.f,0.f,0.f,0.f}; acc[mt][1] = {0.f,0.f,0.f,0.f}; }

#pragma unroll
    for (int ks = 0; ks < 8; ++ks) {
      int Gk = kq * 32 + ks * 4 + lq;
      bf16x8 af[4];
#pragma unroll
      for (int mt = 0; mt < 4; ++mt)
        af[mt] = *(const bf16x8*)&hL[(Gk * 64 + mt * 16 + lr) * 8];
#pragma unroll
      for (int mt = 0; mt < 4; ++mt) {
        acc[mt][0] = __builtin_amdgcn_mfma_f32_16x16x32_bf16(af[mt], Bf[0][ks], acc[mt][0], 0, 0, 0);
        acc[mt][1] = __builtin_amdgcn_mfma_f32_16x16x32_bf16(af[mt], Bf[1][ks], acc[mt][1], 0, 0, 0);
      }
    }
    __syncthreads();  // all hL reads done -> safe to alias P

    // K-split partials -> LDS (stride 34: write 2-way, read 2-way => free)
#pragma unroll
    for (int mt = 0; mt < 4; ++mt)
#pragma unroll
      for (int nt = 0; nt < 2; ++nt)
#pragma unroll
        for (int r = 0; r < 4; ++r) {
          int m = mt * 16 + lq * 4 + r;
          int cc = nt * 16 + lr;
          P[((ng * 4 + kq) * 64 + m) * 34 + cc] = acc[mt][nt][r];
        }
    __syncthreads();

    float hv[2];
#pragma unroll
    for (int p = 0; p < 2; ++p) {
      int jl = q * 2 + p;
      float pre[4];
#pragma unroll
      for (int g = 0; g < 4; ++g) {
        int cc = (g & 1) * 16 + jl;
        int base = (g >> 1) * 4 * 64;
        float s = P[(base + 0 * 64 + b) * 34 + cc] + P[(base + 1 * 64 + b) * 34 + cc] +
                  P[(base + 2 * 64 + b) * 34 + cc] + P[(base + 3 * 64 + b) * 34 + cc];
        u16 xh = (u16)(p == 0 ? (xv[g] & 0xFFFFu) : (xv[g] >> 16));
        pre[g] = s + bf2f(xh) + bia[p][g];
      }
      float iv = sigm(pre[0]);
      float fv = sigm(pre[1]);
      float ov = sigm(pre[2]);
      float gv = tanh_(pre[3]);
      float cn = fv * (p == 0 ? cst0 : cst1) + iv * gv;
      if (p == 0) cst0 = cn; else cst1 = cn;
      hv[p] = ov * tanh_(cn);
    }

    float2 f2v; f2v.x = hv[0]; f2v.y = hv[1];
    if (t < T_ - 1) {
      // h broadcast (granule layout, sc1 write-through to LLC)
      u16* hout = hbuf + (size_t)((t + 1) & 1) * 65536;
      u32 hpack = (u32)f2bf(hv[0]) | ((u32)f2bf(hv[1]) << 16);
      st_u32_sc1((u32*)&hout[(size_t)(Gh * 64 + b) * 8 + c8], hpack);
      waitcnt_vm0();      // h stores ack'd at LLC
      __syncthreads();
      if (tid == 0) st_u32_sc1(&flg[w], (u32)(t + 1));
      // out stores AFTER flag -> drain happens during poll (off critical path)
      *(float2*)&out[((size_t)b * 512 + t) * 1024 + w * 16 + q * 2] = f2v;
      if (wave == 0) {    // single-load poll of all 64 flags
        const u32* fp = flg + lane;
        for (;;) {
          u32 a = ld_u32_sc1(fp);
          if (__ballot(a > (u32)t) == ~0ull) break;
          __builtin_amdgcn_s_sleep(1);
        }
      }
      __syncthreads();
      __builtin_amdgcn_fence(__ATOMIC_ACQUIRE, "agent");  // inv stale L1/L2 h lines
    } else {
      *(float2*)&out[((size_t)b * 512 + t) * 1024 + w * 16 + q * 2] = f2v;
      *(float2*)&out[(size_t)BTH + b * 1024 + w * 16 + q * 2] = f2v;          // h_last
      float2 c2v; c2v.x = cst0; c2v.y = cst1;
      *(float2*)&out[(size_t)BTH + B_ * H_ + b * 1024 + w * 16 + q * 2] = c2v; // c_last
    }
  }
}

// ---------------------------------------------------------------- launch
extern "C" void kernel_launch(void* const* d_in, const int* in_sizes, int n_in,
                              void* d_out, int out_size, void* d_ws, size_t ws_size,
                              hipStream_t stream) {
  const float* x  = (const float*)d_in[0];
  const float* Wi = (const float*)d_in[1];
  const float* Wf = (const float*)d_in[2];
  const float* Wo = (const float*)d_in[3];
  const float* Wg = (const float*)d_in[4];
  const float* Ui = (const float*)d_in[5];
  const float* Uf = (const float*)d_in[6];
  const float* Uo = (const float*)d_in[7];
  const float* Ug = (const float*)d_in[8];
  const float* bi = (const float*)d_in[9];
  const float* bf = (const float*)d_in[10];
  const float* bo = (const float*)d_in[11];
  const float* bg = (const float*)d_in[12];
  float* out = (float*)d_out;

  char* ws = (char*)d_ws;
  u16* xb   = (u16*)(ws + OFF_XB);
  u16* Wt   = (u16*)(ws + OFF_WT);
  u16* Ut   = (u16*)(ws + OFF_UT);
  u16* xg   = (u16*)(ws + OFF_XG);
  u16* hbuf = (u16*)(ws + OFF_HB);
  u32* flg  = (u32*)(ws + OFF_FLG);

  k_init<<<64, 256, 0, stream>>>(hbuf, flg);
  k_cvt_x<<<32768, 256, 0, stream>>>((const float4*)x, (ushort4*)xb);
  k_cvt_w<<<2048, 256, 0, stream>>>(Wi, Wf, Wo, Wg, Ui, Uf, Uo, Ug, Wt, Ut);
  k_gemm<<<dim3(32, 256), 256, 0, stream>>>(xb, Wt, xg);
  k_lstm<<<NWG, 512, 0, stream>>>(Ut, xg, hbuf, flg, bi, bf, bo, bg, out);
}